// Round 5
// baseline (135.767 us; speedup 1.0000x reference)
//
#include <hip/hip_runtime.h>
#include <hip/hip_bf16.h>

#define B_ 8
#define T_ 2048
#define E_ 1024
#define H_ 64

typedef __attribute__((ext_vector_type(8))) short short8v;
typedef __attribute__((ext_vector_type(4))) float f32x4;

__device__ __forceinline__ unsigned short bfbits(float f) {
  return __builtin_bit_cast(unsigned short, __float2bfloat16(f));
}

// ---- prep: Wt[m][c][k] = Wm[k][c] (bf16), q-scale folded into m==1 ----
__global__ __launch_bounds__(256) void prep_wt(
    const float* __restrict__ Wk, const float* __restrict__ Wq,
    const float* __restrict__ Wv, __hip_bfloat16* __restrict__ Wt) {
  const int idx = blockIdx.x * 256 + threadIdx.x;  // 3*64*1024
  const int k = idx & 1023;
  const int c = (idx >> 10) & 63;
  const int m = idx >> 16;
  const float* W = (m == 0) ? Wk : (m == 1) ? Wq : Wv;
  float v = W[k * H_ + c];
  if (m == 1) v *= 0.03125f;  // 1024^-0.5
  Wt[idx] = __float2bfloat16(v);
}

// ---- projection: barrier-free direct-register streaming GEMM ----
// grid 512, block 512 = 8 independent waves: (rowg 0..1) x (colg 0..3)
// wave computes 16 rows x 16 cols of each of K,Q,V over K=1024.
__global__ __launch_bounds__(512, 4) void proj_mfma(
    const float* __restrict__ x, const __hip_bfloat16* __restrict__ Wt,
    __hip_bfloat16* __restrict__ Qb, __hip_bfloat16* __restrict__ Kb,
    __hip_bfloat16* __restrict__ Vt) {
  __shared__ __hip_bfloat16 rep[8][16][24];
  const int tid = threadIdx.x;
  const int lane = tid & 63;
  const int w = tid >> 6;          // 0..7
  const int rowg = w >> 2;         // 0..1
  const int colg = w & 3;          // 0..3
  const int r = lane & 15, g = lane >> 4;
  const int r0 = blockIdx.x * 32;
  const int rw0 = r0 + rowg * 16;  // wave's 16-row base

  f32x4 acc[3];
  #pragma unroll
  for (int m = 0; m < 3; ++m) acc[m] = (f32x4){0.f, 0.f, 0.f, 0.f};

  const float* xr = x + (size_t)(rw0 + r) * E_;
  const __hip_bfloat16* wb = Wt + (size_t)(colg * 16 + r) * E_;

  #pragma unroll 2
  for (int kc = 0; kc < E_; kc += 32) {
    const int ko = kc + g * 8;
    const float4 al = *reinterpret_cast<const float4*>(xr + ko);
    const float4 ah = *reinterpret_cast<const float4*>(xr + ko + 4);
    short8v A;
    A[0] = (short)bfbits(al.x); A[1] = (short)bfbits(al.y);
    A[2] = (short)bfbits(al.z); A[3] = (short)bfbits(al.w);
    A[4] = (short)bfbits(ah.x); A[5] = (short)bfbits(ah.y);
    A[6] = (short)bfbits(ah.z); A[7] = (short)bfbits(ah.w);
    #pragma unroll
    for (int m = 0; m < 3; ++m) {
      const short8v bf = *reinterpret_cast<const short8v*>(wb + (size_t)m * 64 * E_ + ko);
      acc[m] = __builtin_amdgcn_mfma_f32_16x16x32_bf16(A, bf, acc[m], 0, 0, 0);
    }
  }

  // K (m=0), Q (m=1): repack C-frag -> row-major via per-wave LDS
  __hip_bfloat16* rp = &rep[w][0][0];
  #pragma unroll
  for (int m = 0; m < 2; ++m) {
    __hip_bfloat16* Pout = (m == 0) ? Kb : Qb;
    #pragma unroll
    for (int reg = 0; reg < 4; ++reg)
      rp[(g * 4 + reg) * 24 + r] = __float2bfloat16(acc[m][reg]);
    asm volatile("s_waitcnt lgkmcnt(0)" ::: "memory");
    __builtin_amdgcn_sched_barrier(0);
    if (lane < 32) {
      const int row = lane >> 1, ch = lane & 1;
      *(uint4*)(Pout + (size_t)(rw0 + row) * H_ + colg * 16 + ch * 8) =
          *(const uint4*)(rp + row * 24 + ch * 8);
    }
    asm volatile("s_waitcnt lgkmcnt(0)" ::: "memory");
    __builtin_amdgcn_sched_barrier(0);
  }
  // V: direct transposed write Vt[b][h][t]
  const int b = r0 >> 11;
  const int tt = (r0 & 2047) + rowg * 16 + g * 4;
  ushort4 pk;
  pk.x = bfbits(acc[2][0]); pk.y = bfbits(acc[2][1]);
  pk.z = bfbits(acc[2][2]); pk.w = bfbits(acc[2][3]);
  *(ushort4*)(Vt + (size_t)(b * 64 + colg * 16 + r) * T_ + tt) = pk;
}

// ---- attention: barrier-free, swapped-QK, in-block key-split, defer-max ----
// grid 1024 = 128 qtiles x 8 batches (blk = i*8+b pins batch b to XCD b)
// qtile map interleaves light/heavy so concurrent blocks balance.
__global__ __launch_bounds__(128, 2) void attn_mfma(
    const __hip_bfloat16* __restrict__ Qb, const __hip_bfloat16* __restrict__ Kb,
    const __hip_bfloat16* __restrict__ Vt, float* __restrict__ out) {
  __shared__ __hip_bfloat16 Ps[2][16][72];
  __shared__ float cmb[64][20];
  __shared__ float ml[16][2];
  const int tid = threadIdx.x;
  const int lane = tid & 63;
  const int w = tid >> 6;
  const int r = lane & 15, g = lane >> 4;
  const int blk = blockIdx.x;
  const int b = blk & 7;
  const int i = blk >> 3;  // 0..127
  const int seg = i & 3, pos = i >> 2;
  const int qt = (seg == 0) ? pos : (seg == 1) ? (63 - pos)
               : (seg == 2) ? (64 + pos) : (127 - pos);
  const int q0 = qt * 16;
  const size_t tb = (size_t)b * T_;
  const int bb = b * 64;

  const short8v qf0 = *(const short8v*)(Qb + (tb + q0 + r) * H_ + g * 8);
  const short8v qf1 = *(const short8v*)(Qb + (tb + q0 + r) * H_ + 32 + g * 8);

  f32x4 o[4];
  #pragma unroll
  for (int k2 = 0; k2 < 4; ++k2) o[k2] = (f32x4){0.f, 0.f, 0.f, 0.f};
  float mrun = -1e30f, lrun = 0.f;

  const int nt = (qt >> 2) + 1;
  const int h_ = (nt + 1) >> 1;
  const int t0 = w ? h_ : 0;
  const int t1 = w ? nt : h_;

  short8v kbA[4][2], kbB[4][2];
  auto loadK = [&](int t, short8v (&kb)[4][2]) {
    #pragma unroll
    for (int kg = 0; kg < 4; ++kg)
      #pragma unroll
      for (int c = 0; c < 2; ++c)
        kb[kg][c] = *(const short8v*)(Kb + (tb + t * 64 + kg * 16 + r) * H_ + c * 32 + g * 8);
  };

  auto body = [&](int t, short8v (&kbU)[4][2], short8v (&kbP)[4][2]) {
    // issue V(t) early; used after softmax
    short8v vb[4][2];
    #pragma unroll
    for (int hg = 0; hg < 4; ++hg)
      #pragma unroll
      for (int c = 0; c < 2; ++c)
        vb[hg][c] = *(const short8v*)(
            Vt + (size_t)(bb + hg * 16 + r) * T_ + t * 64 + c * 32 + g * 8);
    if (t + 1 < t1) loadK(t + 1, kbP);  // prefetch next K

    // QK^T swapped: lane holds q = q0+r, keys kg*16 + g*4 + reg
    f32x4 s[4];
    #pragma unroll
    for (int k2 = 0; k2 < 4; ++k2) s[k2] = (f32x4){0.f, 0.f, 0.f, 0.f};
    __builtin_amdgcn_s_setprio(1);
    #pragma unroll
    for (int kg = 0; kg < 4; ++kg) {
      s[kg] = __builtin_amdgcn_mfma_f32_16x16x32_bf16(kbU[kg][0], qf0, s[kg], 0, 0, 0);
      s[kg] = __builtin_amdgcn_mfma_f32_16x16x32_bf16(kbU[kg][1], qf1, s[kg], 0, 0, 0);
    }
    __builtin_amdgcn_s_setprio(0);

    if (t == nt - 1) {  // diagonal tile only
      #pragma unroll
      for (int kg = 0; kg < 4; ++kg)
        #pragma unroll
        for (int reg = 0; reg < 4; ++reg)
          if (t * 64 + kg * 16 + g * 4 + reg > q0 + r) s[kg][reg] = -1e30f;
    }

    // online softmax with defer-max (skip reduce+rescale when max grew < 8)
    float pmax = s[0][0];
    #pragma unroll
    for (int kg = 0; kg < 4; ++kg)
      #pragma unroll
      for (int reg = 0; reg < 4; ++reg) pmax = fmaxf(pmax, s[kg][reg]);
    if (!__all(pmax - mrun <= 8.0f)) {
      float pm = fmaxf(pmax, __shfl_xor(pmax, 16));
      pm = fmaxf(pm, __shfl_xor(pm, 32));
      const float nm = fmaxf(mrun, pm);
      const float al = __expf(mrun - nm);
      mrun = nm;
      lrun *= al;
      #pragma unroll
      for (int hg = 0; hg < 4; ++hg) o[hg] *= al;
    }
    float p[4][4];
    float rs = 0.f;
    #pragma unroll
    for (int kg = 0; kg < 4; ++kg)
      #pragma unroll
      for (int reg = 0; reg < 4; ++reg) {
        p[kg][reg] = __expf(s[kg][reg] - mrun);
        rs += p[kg][reg];
      }
    rs += __shfl_xor(rs, 16);
    rs += __shfl_xor(rs, 32);
    lrun += rs;

    // P -> Ps[q][key] (packed b64 writes), read back as PV Y-fragment
    #pragma unroll
    for (int kg = 0; kg < 4; ++kg) {
      ushort4 u;
      u.x = bfbits(p[kg][0]); u.y = bfbits(p[kg][1]);
      u.z = bfbits(p[kg][2]); u.w = bfbits(p[kg][3]);
      *(ushort4*)&Ps[w][r][kg * 16 + g * 4] = u;
    }
    asm volatile("s_waitcnt lgkmcnt(0)" ::: "memory");
    __builtin_amdgcn_sched_barrier(0);
    short8v pf[2];
    pf[0] = *(const short8v*)&Ps[w][r][g * 8];
    pf[1] = *(const short8v*)&Ps[w][r][32 + g * 8];

    // PV: o[hg] (h = hg*16+g*4+reg, q = q0+r)
    __builtin_amdgcn_s_setprio(1);
    #pragma unroll
    for (int c = 0; c < 2; ++c)
      #pragma unroll
      for (int hg = 0; hg < 4; ++hg)
        o[hg] = __builtin_amdgcn_mfma_f32_16x16x32_bf16(vb[hg][c], pf[c], o[hg], 0, 0, 0);
    __builtin_amdgcn_s_setprio(0);
  };

  if (t0 < t1) {
    loadK(t0, kbA);
    int t = t0;
    while (true) {
      body(t, kbA, kbB);
      if (++t >= t1) break;
      body(t, kbB, kbA);
      if (++t >= t1) break;
    }
  }

  // combine the two waves' partials
  if (w == 1) {
    if (g == 0) { ml[r][0] = mrun; ml[r][1] = lrun; }
    #pragma unroll
    for (int hg = 0; hg < 4; ++hg) *(f32x4*)&cmb[lane][hg * 4] = o[hg];
  }
  __syncthreads();
  if (w == 0) {
    const float m1 = ml[r][0], l1 = ml[r][1];
    const float mm = fmaxf(mrun, m1);
    const float sc0 = __expf(mrun - mm), sc1 = __expf(m1 - mm);
    const float inv = 1.f / (lrun * sc0 + l1 * sc1);
    #pragma unroll
    for (int hg = 0; hg < 4; ++hg) {
      const f32x4 o1 = *(const f32x4*)&cmb[lane][hg * 4];
      f32x4 res = (o[hg] * sc0 + o1 * sc1) * inv;
      *(f32x4*)(out + (tb + q0 + r) * H_ + hg * 16 + g * 4) = res;
    }
  }
}

extern "C" void kernel_launch(void* const* d_in, const int* in_sizes, int n_in,
                              void* d_out, int out_size, void* d_ws, size_t ws_size,
                              hipStream_t stream) {
  const float* x  = (const float*)d_in[0];
  const float* Wk = (const float*)d_in[1];
  const float* Wq = (const float*)d_in[2];
  const float* Wv = (const float*)d_in[3];
  float* out = (float*)d_out;

  __hip_bfloat16* Qb = (__hip_bfloat16*)d_ws;
  __hip_bfloat16* Kb = Qb + (size_t)B_ * T_ * H_;
  __hip_bfloat16* Vt = Kb + (size_t)B_ * T_ * H_;   // [B][64][T]
  __hip_bfloat16* Wt = Vt + (size_t)B_ * T_ * H_;   // [3][64][1024]

  prep_wt<<<(3 * H_ * E_) / 256, 256, 0, stream>>>(Wk, Wq, Wv, Wt);
  proj_mfma<<<(B_ * T_) / 32, 512, 0, stream>>>(x, Wt, Qb, Kb, Vt);
  attn_mfma<<<B_ * (T_ / 16), 128, 0, stream>>>(Qb, Kb, Vt, out);
}

// Round 6
// 64.874 us; speedup vs baseline: 2.0928x; 2.0928x over previous
//
#include <hip/hip_runtime.h>
#include <hip/hip_bf16.h>

#define B_ 8
#define T_ 2048
#define E_ 1024
#define H_ 64

typedef __attribute__((ext_vector_type(8))) short short8v;
typedef __attribute__((ext_vector_type(4))) float f32x4;

__device__ __forceinline__ unsigned short bfbits(float f) {
  return __builtin_bit_cast(unsigned short, __float2bfloat16(f));
}

__device__ __forceinline__ void gload_lds16(const void* g, void* l) {
  __builtin_amdgcn_global_load_lds(
      (const __attribute__((address_space(1))) unsigned*)g,
      (__attribute__((address_space(3))) unsigned*)l, 16, 0, 0);
}

// ---- prep: Wf = fragment-major W (bf16). frag cf in 0..11 (K:0-3 Q:4-7 V:8-11),
// kb in 0..31 (K-blocks of 32). Element (lane l, j): col=(cf&3)*16+(l&15),
// k=kb*32+(l>>4)*8+j. Each frag is a contiguous 1KB MFMA B-operand.
__global__ __launch_bounds__(256) void prep_wf(
    const float* __restrict__ Wk, const float* __restrict__ Wq,
    const float* __restrict__ Wv, __hip_bfloat16* __restrict__ Wf) {
  const int idx = blockIdx.x * 256 + threadIdx.x;  // 12*32*512 = 196608
  const int f = idx >> 9;
  const int e = idx & 511;
  const int l = e >> 3, j = e & 7;
  const int cf = f >> 5, kb = f & 31;
  const int m = cf >> 2;
  const int c = (cf & 3) * 16 + (l & 15);
  const int k = kb * 32 + (l >> 4) * 8 + j;
  const float* W = (m == 0) ? Wk : (m == 1) ? Wq : Wv;
  float v = W[k * H_ + c];
  if (m == 1) v *= 0.03125f;  // 1024^-0.5
  Wf[idx] = __float2bfloat16(v);
}

// ---- projection: x staged (gload_lds dbuf), W register-pipelined from Wf ----
// grid 512, block 512 = 8 waves: (rowg = w>>2) x (colh = w&3).
// wave: 16 rows x 48 cols (cf = colh*3..+2) over K=1024, BK=64 steps.
__global__ __launch_bounds__(512) void proj_mfma(
    const float* __restrict__ x, const __hip_bfloat16* __restrict__ Wf,
    __hip_bfloat16* __restrict__ Qb, __hip_bfloat16* __restrict__ Kb,
    __hip_bfloat16* __restrict__ Vt) {
  __shared__ float xs[2][32][64];            // 16 KB, slot16-swizzled by row&7
  __shared__ __hip_bfloat16 rep[8][16][24];  // 6 KB epilogue repack
  const int tid = threadIdx.x;
  const int lane = tid & 63;
  const int w = tid >> 6;
  const int rowg = w >> 2;
  const int colh = w & 3;
  const int cf0 = colh * 3;
  const int r = lane & 15, g = lane >> 4;
  const int r0 = blockIdx.x * 32;
  const int rw0 = r0 + rowg * 16;

  f32x4 acc[3];
  #pragma unroll
  for (int i = 0; i < 3; ++i) acc[i] = (f32x4){0.f, 0.f, 0.f, 0.f};

  auto stage = [&](int buf, int kc) {  // 1 gload_lds per wave, 8 cover 32x64 f32
    const int row = w * 4 + (lane >> 4);
    const int sl = lane & 15;
    const int ssl = (sl & 8) | ((sl & 7) ^ (row & 7));
    gload_lds16(x + (size_t)(r0 + row) * E_ + kc + ssl * 4, &xs[buf][w * 4][0]);
  };

  auto loadW = [&](int t, short8v (&Wn)[3][2]) {  // 6 contiguous 1KB frag loads
    #pragma unroll
    for (int i = 0; i < 3; ++i)
      #pragma unroll
      for (int h = 0; h < 2; ++h)
        Wn[i][h] = *(const short8v*)(
            Wf + (((size_t)(cf0 + i) * 32 + t * 2 + h) << 9) + lane * 8);
  };

  auto computeStep = [&](int buf, short8v (&Wc)[3][2]) {
    const char* base = (const char*)&xs[buf][0][0] + (rowg * 16 + r) * 256;
    #pragma unroll
    for (int h = 0; h < 2; ++h) {
      const int s0 = h * 8 + ((2 * g + 0) ^ (r & 7));
      const int s1 = h * 8 + ((2 * g + 1) ^ (r & 7));
      const f32x4 lo = *(const f32x4*)(base + s0 * 16);
      const f32x4 hi = *(const f32x4*)(base + s1 * 16);
      short8v A;
      A[0] = (short)bfbits(lo[0]); A[1] = (short)bfbits(lo[1]);
      A[2] = (short)bfbits(lo[2]); A[3] = (short)bfbits(lo[3]);
      A[4] = (short)bfbits(hi[0]); A[5] = (short)bfbits(hi[1]);
      A[6] = (short)bfbits(hi[2]); A[7] = (short)bfbits(hi[3]);
      #pragma unroll
      for (int i = 0; i < 3; ++i)
        acc[i] = __builtin_amdgcn_mfma_f32_16x16x32_bf16(A, Wc[i][h], acc[i], 0, 0, 0);
    }
  };

  short8v WA[3][2], WB[3][2];
  stage(0, 0);
  __builtin_amdgcn_sched_barrier(0);
  loadW(0, WA);
  asm volatile("s_waitcnt vmcnt(0)" ::: "memory");
  __builtin_amdgcn_s_barrier();

  for (int t = 0; t < 16; t += 2) {
    // even half: compute step t from xs[0]/WA; prefetch step t+1
    stage(1, (t + 1) * 64);
    __builtin_amdgcn_sched_barrier(0);
    loadW(t + 1, WB);
    computeStep(0, WA);
    asm volatile("s_waitcnt vmcnt(6)" ::: "memory");  // 6 = WB in flight
    __builtin_amdgcn_s_barrier();
    // odd half: compute step t+1 from xs[1]/WB; prefetch step t+2
    if (t + 2 <= 15) {
      stage(0, (t + 2) * 64);
      __builtin_amdgcn_sched_barrier(0);
      loadW(t + 2, WA);
    }
    computeStep(1, WB);
    if (t + 2 < 16) {
      asm volatile("s_waitcnt vmcnt(6)" ::: "memory");
      __builtin_amdgcn_s_barrier();
    }
  }

  // epilogue: per-wave repack K/Q to row-major; V direct transposed
  __hip_bfloat16* rp = &rep[w][0][0];
  #pragma unroll
  for (int i = 0; i < 3; ++i) {
    const int cf = cf0 + i;
    const int m = cf >> 2;
    const int c0 = (cf & 3) * 16;
    if (m < 2) {
      __hip_bfloat16* Pout = (m == 0) ? Kb : Qb;
      #pragma unroll
      for (int reg = 0; reg < 4; ++reg)
        rp[(g * 4 + reg) * 24 + r] = __float2bfloat16(acc[i][reg]);
      asm volatile("s_waitcnt lgkmcnt(0)" ::: "memory");
      __builtin_amdgcn_sched_barrier(0);
      if (lane < 32) {
        const int row = lane >> 1, ch = lane & 1;
        *(uint4*)(Pout + (size_t)(rw0 + row) * H_ + c0 + ch * 8) =
            *(const uint4*)(rp + row * 24 + ch * 8);
      }
      asm volatile("s_waitcnt lgkmcnt(0)" ::: "memory");
      __builtin_amdgcn_sched_barrier(0);
    } else {
      const int b = r0 >> 11;
      const int tt = (rw0 & 2047) + g * 4;
      ushort4 pk;
      pk.x = bfbits(acc[i][0]); pk.y = bfbits(acc[i][1]);
      pk.z = bfbits(acc[i][2]); pk.w = bfbits(acc[i][3]);
      *(ushort4*)(Vt + (size_t)(b * 64 + c0 + r) * T_ + tt) = pk;
    }
  }
}

// ---- attention: barrier-free, swapped-QK, in-block key-split (round-4 exact) ----
__global__ __launch_bounds__(128, 2) void attn_mfma(
    const __hip_bfloat16* __restrict__ Qb, const __hip_bfloat16* __restrict__ Kb,
    const __hip_bfloat16* __restrict__ Vt, float* __restrict__ out) {
  __shared__ __hip_bfloat16 Ps[2][16][72];
  __shared__ float cmb[64][20];
  __shared__ float ml[16][2];
  const int tid = threadIdx.x;
  const int lane = tid & 63;
  const int w = tid >> 6;
  const int r = lane & 15, g = lane >> 4;
  const int blk = blockIdx.x;
  const int b = blk & 7;
  const int i = blk >> 3;  // 0..127
  const int s_ = i >> 5, j_ = i & 31;
  const int qt = (s_ == 0) ? j_ : (s_ == 1) ? (63 - j_) : (s_ == 2) ? (64 + j_) : (127 - j_);
  const int q0 = qt * 16;
  const size_t tb = (size_t)b * T_;
  const int bb = b * 64;

  const short8v qf0 = *(const short8v*)(Qb + (tb + q0 + r) * H_ + g * 8);
  const short8v qf1 = *(const short8v*)(Qb + (tb + q0 + r) * H_ + 32 + g * 8);

  f32x4 o[4];
  #pragma unroll
  for (int k2 = 0; k2 < 4; ++k2) o[k2] = (f32x4){0.f, 0.f, 0.f, 0.f};
  float mrun = -1e30f, lrun = 0.f;

  const int nt = (qt >> 2) + 1;
  const int h_ = (nt + 1) >> 1;
  const int t0 = w ? h_ : 0;
  const int t1 = w ? nt : h_;

  short8v kbA[4][2], kbB[4][2];
  auto loadK = [&](int t, short8v (&kb)[4][2]) {
    #pragma unroll
    for (int kg = 0; kg < 4; ++kg)
      #pragma unroll
      for (int c = 0; c < 2; ++c)
        kb[kg][c] = *(const short8v*)(Kb + (tb + t * 64 + kg * 16 + r) * H_ + c * 32 + g * 8);
  };

  auto body = [&](int t, short8v (&kbU)[4][2], short8v (&kbP)[4][2]) {
    short8v vb[4][2];
    #pragma unroll
    for (int hg = 0; hg < 4; ++hg)
      #pragma unroll
      for (int c = 0; c < 2; ++c)
        vb[hg][c] = *(const short8v*)(
            Vt + (size_t)(bb + hg * 16 + r) * T_ + t * 64 + c * 32 + g * 8);
    if (t + 1 < t1) loadK(t + 1, kbP);

    f32x4 s[4];
    #pragma unroll
    for (int k2 = 0; k2 < 4; ++k2) s[k2] = (f32x4){0.f, 0.f, 0.f, 0.f};
    __builtin_amdgcn_s_setprio(1);
    #pragma unroll
    for (int kg = 0; kg < 4; ++kg) {
      s[kg] = __builtin_amdgcn_mfma_f32_16x16x32_bf16(kbU[kg][0], qf0, s[kg], 0, 0, 0);
      s[kg] = __builtin_amdgcn_mfma_f32_16x16x32_bf16(kbU[kg][1], qf1, s[kg], 0, 0, 0);
    }
    __builtin_amdgcn_s_setprio(0);

    if (t == nt - 1) {
      #pragma unroll
      for (int kg = 0; kg < 4; ++kg)
        #pragma unroll
        for (int reg = 0; reg < 4; ++reg)
          if (t * 64 + kg * 16 + g * 4 + reg > q0 + r) s[kg][reg] = -1e30f;
    }

    float pm = s[0][0];
    #pragma unroll
    for (int kg = 0; kg < 4; ++kg)
      #pragma unroll
      for (int reg = 0; reg < 4; ++reg) pm = fmaxf(pm, s[kg][reg]);
    pm = fmaxf(pm, __shfl_xor(pm, 16));
    pm = fmaxf(pm, __shfl_xor(pm, 32));
    const float nm = fmaxf(mrun, pm);
    const float al = __expf(mrun - nm);
    mrun = nm;
    float p[4][4];
    float rs = 0.f;
    #pragma unroll
    for (int kg = 0; kg < 4; ++kg)
      #pragma unroll
      for (int reg = 0; reg < 4; ++reg) {
        p[kg][reg] = __expf(s[kg][reg] - nm);
        rs += p[kg][reg];
      }
    rs += __shfl_xor(rs, 16);
    rs += __shfl_xor(rs, 32);
    lrun = lrun * al + rs;
    #pragma unroll
    for (int hg = 0; hg < 4; ++hg) o[hg] *= al;

    #pragma unroll
    for (int kg = 0; kg < 4; ++kg) {
      ushort4 u;
      u.x = bfbits(p[kg][0]); u.y = bfbits(p[kg][1]);
      u.z = bfbits(p[kg][2]); u.w = bfbits(p[kg][3]);
      *(ushort4*)&Ps[w][r][kg * 16 + g * 4] = u;
    }
    short8v pf[2];
    pf[0] = *(const short8v*)&Ps[w][r][g * 8];
    pf[1] = *(const short8v*)&Ps[w][r][32 + g * 8];

    __builtin_amdgcn_s_setprio(1);
    #pragma unroll
    for (int c = 0; c < 2; ++c)
      #pragma unroll
      for (int hg = 0; hg < 4; ++hg)
        o[hg] = __builtin_amdgcn_mfma_f32_16x16x32_bf16(vb[hg][c], pf[c], o[hg], 0, 0, 0);
    __builtin_amdgcn_s_setprio(0);
  };

  if (t0 < t1) {
    loadK(t0, kbA);
    int t = t0;
    while (true) {
      body(t, kbA, kbB);
      if (++t >= t1) break;
      body(t, kbB, kbA);
      if (++t >= t1) break;
    }
  }

  if (w == 1) {
    if (g == 0) { ml[r][0] = mrun; ml[r][1] = lrun; }
    #pragma unroll
    for (int hg = 0; hg < 4; ++hg) *(f32x4*)&cmb[lane][hg * 4] = o[hg];
  }
  __syncthreads();
  if (w == 0) {
    const float m1 = ml[r][0], l1 = ml[r][1];
    const float mm = fmaxf(mrun, m1);
    const float sc0 = __expf(mrun - mm), sc1 = __expf(m1 - mm);
    const float inv = 1.f / (lrun * sc0 + l1 * sc1);
    #pragma unroll
    for (int hg = 0; hg < 4; ++hg) {
      const f32x4 o1 = *(const f32x4*)&cmb[lane][hg * 4];
      f32x4 res = (o[hg] * sc0 + o1 * sc1) * inv;
      *(f32x4*)(out + (tb + q0 + r) * H_ + hg * 16 + g * 4) = res;
    }
  }
}

extern "C" void kernel_launch(void* const* d_in, const int* in_sizes, int n_in,
                              void* d_out, int out_size, void* d_ws, size_t ws_size,
                              hipStream_t stream) {
  const float* x  = (const float*)d_in[0];
  const float* Wk = (const float*)d_in[1];
  const float* Wq = (const float*)d_in[2];
  const float* Wv = (const float*)d_in[3];
  float* out = (float*)d_out;

  __hip_bfloat16* Qb = (__hip_bfloat16*)d_ws;
  __hip_bfloat16* Kb = Qb + (size_t)B_ * T_ * H_;
  __hip_bfloat16* Vt = Kb + (size_t)B_ * T_ * H_;   // [B][64][T]
  __hip_bfloat16* Wf = Vt + (size_t)B_ * T_ * H_;   // fragment-major W, 384 KB

  prep_wf<<<(12 * 32 * 512) / 256, 256, 0, stream>>>(Wk, Wq, Wv, Wf);
  proj_mfma<<<(B_ * T_) / 32, 512, 0, stream>>>(x, Wf, Qb, Kb, Vt);
  attn_mfma<<<B_ * (T_ / 16), 128, 0, stream>>>(Qb, Kb, Vt, out);
}

// Round 7
// 64.022 us; speedup vs baseline: 2.1206x; 1.0133x over previous
//
#include <hip/hip_runtime.h>
#include <hip/hip_bf16.h>

#define B_ 8
#define T_ 2048
#define E_ 1024
#define H_ 64

typedef __attribute__((ext_vector_type(8))) short short8v;
typedef __attribute__((ext_vector_type(4))) float f32x4;

__device__ __forceinline__ unsigned short bfbits(float f) {
  return __builtin_bit_cast(unsigned short, __float2bfloat16(f));
}

__device__ __forceinline__ void gload_lds16(const void* g, void* l) {
  __builtin_amdgcn_global_load_lds(
      (const __attribute__((address_space(1))) unsigned*)g,
      (__attribute__((address_space(3))) unsigned*)l, 16, 0, 0);
}

// ---- prep: Wf = fragment-major W (bf16). frag cf in 0..11 (K:0-3 Q:4-7 V:8-11),
// kb in 0..31 (K-blocks of 32). Element (lane l, j): col=(cf&3)*16+(l&15),
// k=kb*32+(l>>4)*8+j. Each frag is a contiguous 1KB MFMA B-operand.
__global__ __launch_bounds__(256) void prep_wf(
    const float* __restrict__ Wk, const float* __restrict__ Wq,
    const float* __restrict__ Wv, __hip_bfloat16* __restrict__ Wf) {
  const int idx = blockIdx.x * 256 + threadIdx.x;  // 12*32*512 = 196608
  const int f = idx >> 9;
  const int e = idx & 511;
  const int l = e >> 3, j = e & 7;
  const int cf = f >> 5, kb = f & 31;
  const int m = cf >> 2;
  const int c = (cf & 3) * 16 + (l & 15);
  const int k = kb * 32 + (l >> 4) * 8 + j;
  const float* W = (m == 0) ? Wk : (m == 1) ? Wq : Wv;
  float v = W[k * H_ + c];
  if (m == 1) v *= 0.03125f;  // 1024^-0.5
  Wf[idx] = __float2bfloat16(v);
}

// ---- projection: x staged via gload_lds, 4-buffer distance-3 pipeline;
// W register-pipelined from fragment-major Wf. grid 512, block 512 = 8 waves.
__global__ __launch_bounds__(512) void proj_mfma(
    const float* __restrict__ x, const __hip_bfloat16* __restrict__ Wf,
    __hip_bfloat16* __restrict__ Qb, __hip_bfloat16* __restrict__ Kb,
    __hip_bfloat16* __restrict__ Vt) {
  __shared__ float xs[4][32][64];            // 32 KB, slot16-swizzled by row&7
  __shared__ __hip_bfloat16 rep[8][16][24];  // 6 KB epilogue repack
  const int tid = threadIdx.x;
  const int lane = tid & 63;
  const int w = tid >> 6;
  const int rowg = w >> 2;
  const int colh = w & 3;
  const int cf0 = colh * 3;
  const int r = lane & 15, g = lane >> 4;
  const int r0 = blockIdx.x * 32;
  const int rw0 = r0 + rowg * 16;

  f32x4 acc[3];
  #pragma unroll
  for (int i = 0; i < 3; ++i) acc[i] = (f32x4){0.f, 0.f, 0.f, 0.f};

  auto stage = [&](int buf, int kc) {  // 1 gload_lds per wave; 8 cover 32x64 f32
    const int row = w * 4 + (lane >> 4);
    const int sl = lane & 15;
    const int ssl = (sl & 8) | ((sl & 7) ^ (row & 7));
    gload_lds16(x + (size_t)(r0 + row) * E_ + kc + ssl * 4, &xs[buf][w * 4][0]);
  };

  auto loadW = [&](int t, short8v (&Wn)[3][2]) {  // 6 contiguous 1KB frag loads
    #pragma unroll
    for (int i = 0; i < 3; ++i)
      #pragma unroll
      for (int h = 0; h < 2; ++h)
        Wn[i][h] = *(const short8v*)(
            Wf + (((size_t)(cf0 + i) * 32 + t * 2 + h) << 9) + lane * 8);
  };

  auto computeStep = [&](int buf, short8v (&Wc)[3][2]) {
    const char* base = (const char*)&xs[buf][0][0] + (rowg * 16 + r) * 256;
    #pragma unroll
    for (int h = 0; h < 2; ++h) {
      const int s0 = h * 8 + ((2 * g + 0) ^ (r & 7));
      const int s1 = h * 8 + ((2 * g + 1) ^ (r & 7));
      const f32x4 lo = *(const f32x4*)(base + s0 * 16);
      const f32x4 hi = *(const f32x4*)(base + s1 * 16);
      short8v A;
      A[0] = (short)bfbits(lo[0]); A[1] = (short)bfbits(lo[1]);
      A[2] = (short)bfbits(lo[2]); A[3] = (short)bfbits(lo[3]);
      A[4] = (short)bfbits(hi[0]); A[5] = (short)bfbits(hi[1]);
      A[6] = (short)bfbits(hi[2]); A[7] = (short)bfbits(hi[3]);
      #pragma unroll
      for (int i = 0; i < 3; ++i)
        acc[i] = __builtin_amdgcn_mfma_f32_16x16x32_bf16(A, Wc[i][h], acc[i], 0, 0, 0);
    }
  };

  short8v WA[3][2], WB[3][2];
  loadW(0, WA);
  stage(0, 0);
  stage(1, 64);
  stage(2, 128);
  asm volatile("s_waitcnt vmcnt(2)" ::: "memory");  // WA + stage(0) done; s1,s2 fly
  __builtin_amdgcn_s_barrier();

  for (int t = 0; t < 16; t += 2) {
    // even step t: compute xs[t&3] with WA; prefetch stage(t+3), W(t+1)
    if (t + 3 < 16) stage((t + 3) & 3, (t + 3) * 64);
    loadW(t + 1, WB);
    computeStep(t & 3, WA);
    // drain stage(t+1): outstanding newer = s(t+2),s(t+3),W(t+1)x6
    if (t < 14) asm volatile("s_waitcnt vmcnt(8)" ::: "memory");
    else        asm volatile("s_waitcnt vmcnt(6)" ::: "memory");
    __builtin_amdgcn_s_barrier();
    // odd step t+1: compute xs[(t+1)&3] with WB; prefetch stage(t+4), W(t+2)
    if (t + 4 < 16) stage((t + 4) & 3, (t + 4) * 64);
    if (t + 2 < 16) loadW(t + 2, WA);
    computeStep((t + 1) & 3, WB);
    if (t < 12) {
      asm volatile("s_waitcnt vmcnt(8)" ::: "memory");
      __builtin_amdgcn_s_barrier();
    } else if (t == 12) {
      asm volatile("s_waitcnt vmcnt(7)" ::: "memory");
      __builtin_amdgcn_s_barrier();
    }  // t == 14: last step, no barrier needed
  }

  // epilogue: per-wave repack K/Q to row-major; V direct transposed
  __hip_bfloat16* rp = &rep[w][0][0];
  #pragma unroll
  for (int i = 0; i < 3; ++i) {
    const int cf = cf0 + i;
    const int m = cf >> 2;
    const int c0 = (cf & 3) * 16;
    if (m < 2) {
      __hip_bfloat16* Pout = (m == 0) ? Kb : Qb;
      #pragma unroll
      for (int reg = 0; reg < 4; ++reg)
        rp[(g * 4 + reg) * 24 + r] = __float2bfloat16(acc[i][reg]);
      asm volatile("s_waitcnt lgkmcnt(0)" ::: "memory");
      __builtin_amdgcn_sched_barrier(0);
      if (lane < 32) {
        const int row = lane >> 1, ch = lane & 1;
        *(uint4*)(Pout + (size_t)(rw0 + row) * H_ + c0 + ch * 8) =
            *(const uint4*)(rp + row * 24 + ch * 8);
      }
      asm volatile("s_waitcnt lgkmcnt(0)" ::: "memory");
      __builtin_amdgcn_sched_barrier(0);
    } else {
      const int b = r0 >> 11;
      const int tt = (rw0 & 2047) + g * 4;
      ushort4 pk;
      pk.x = bfbits(acc[i][0]); pk.y = bfbits(acc[i][1]);
      pk.z = bfbits(acc[i][2]); pk.w = bfbits(acc[i][3]);
      *(ushort4*)(Vt + (size_t)(b * 64 + c0 + r) * T_ + tt) = pk;
    }
  }
}

// ---- attention: barrier-free, swapped-QK, in-block key-split (round-4 exact) ----
__global__ __launch_bounds__(128, 2) void attn_mfma(
    const __hip_bfloat16* __restrict__ Qb, const __hip_bfloat16* __restrict__ Kb,
    const __hip_bfloat16* __restrict__ Vt, float* __restrict__ out) {
  __shared__ __hip_bfloat16 Ps[2][16][72];
  __shared__ float cmb[64][20];
  __shared__ float ml[16][2];
  const int tid = threadIdx.x;
  const int lane = tid & 63;
  const int w = tid >> 6;
  const int r = lane & 15, g = lane >> 4;
  const int blk = blockIdx.x;
  const int b = blk & 7;
  const int i = blk >> 3;  // 0..127
  const int s_ = i >> 5, j_ = i & 31;
  const int qt = (s_ == 0) ? j_ : (s_ == 1) ? (63 - j_) : (s_ == 2) ? (64 + j_) : (127 - j_);
  const int q0 = qt * 16;
  const size_t tb = (size_t)b * T_;
  const int bb = b * 64;

  const short8v qf0 = *(const short8v*)(Qb + (tb + q0 + r) * H_ + g * 8);
  const short8v qf1 = *(const short8v*)(Qb + (tb + q0 + r) * H_ + 32 + g * 8);

  f32x4 o[4];
  #pragma unroll
  for (int k2 = 0; k2 < 4; ++k2) o[k2] = (f32x4){0.f, 0.f, 0.f, 0.f};
  float mrun = -1e30f, lrun = 0.f;

  const int nt = (qt >> 2) + 1;
  const int h_ = (nt + 1) >> 1;
  const int t0 = w ? h_ : 0;
  const int t1 = w ? nt : h_;

  short8v kbA[4][2], kbB[4][2];
  auto loadK = [&](int t, short8v (&kb)[4][2]) {
    #pragma unroll
    for (int kg = 0; kg < 4; ++kg)
      #pragma unroll
      for (int c = 0; c < 2; ++c)
        kb[kg][c] = *(const short8v*)(Kb + (tb + t * 64 + kg * 16 + r) * H_ + c * 32 + g * 8);
  };

  auto body = [&](int t, short8v (&kbU)[4][2], short8v (&kbP)[4][2]) {
    short8v vb[4][2];
    #pragma unroll
    for (int hg = 0; hg < 4; ++hg)
      #pragma unroll
      for (int c = 0; c < 2; ++c)
        vb[hg][c] = *(const short8v*)(
            Vt + (size_t)(bb + hg * 16 + r) * T_ + t * 64 + c * 32 + g * 8);
    if (t + 1 < t1) loadK(t + 1, kbP);

    f32x4 s[4];
    #pragma unroll
    for (int k2 = 0; k2 < 4; ++k2) s[k2] = (f32x4){0.f, 0.f, 0.f, 0.f};
    __builtin_amdgcn_s_setprio(1);
    #pragma unroll
    for (int kg = 0; kg < 4; ++kg) {
      s[kg] = __builtin_amdgcn_mfma_f32_16x16x32_bf16(kbU[kg][0], qf0, s[kg], 0, 0, 0);
      s[kg] = __builtin_amdgcn_mfma_f32_16x16x32_bf16(kbU[kg][1], qf1, s[kg], 0, 0, 0);
    }
    __builtin_amdgcn_s_setprio(0);

    if (t == nt - 1) {
      #pragma unroll
      for (int kg = 0; kg < 4; ++kg)
        #pragma unroll
        for (int reg = 0; reg < 4; ++reg)
          if (t * 64 + kg * 16 + g * 4 + reg > q0 + r) s[kg][reg] = -1e30f;
    }

    float pm = s[0][0];
    #pragma unroll
    for (int kg = 0; kg < 4; ++kg)
      #pragma unroll
      for (int reg = 0; reg < 4; ++reg) pm = fmaxf(pm, s[kg][reg]);
    pm = fmaxf(pm, __shfl_xor(pm, 16));
    pm = fmaxf(pm, __shfl_xor(pm, 32));
    const float nm = fmaxf(mrun, pm);
    const float al = __expf(mrun - nm);
    mrun = nm;
    float p[4][4];
    float rs = 0.f;
    #pragma unroll
    for (int kg = 0; kg < 4; ++kg)
      #pragma unroll
      for (int reg = 0; reg < 4; ++reg) {
        p[kg][reg] = __expf(s[kg][reg] - nm);
        rs += p[kg][reg];
      }
    rs += __shfl_xor(rs, 16);
    rs += __shfl_xor(rs, 32);
    lrun = lrun * al + rs;
    #pragma unroll
    for (int hg = 0; hg < 4; ++hg) o[hg] *= al;

    #pragma unroll
    for (int kg = 0; kg < 4; ++kg) {
      ushort4 u;
      u.x = bfbits(p[kg][0]); u.y = bfbits(p[kg][1]);
      u.z = bfbits(p[kg][2]); u.w = bfbits(p[kg][3]);
      *(ushort4*)&Ps[w][r][kg * 16 + g * 4] = u;
    }
    short8v pf[2];
    pf[0] = *(const short8v*)&Ps[w][r][g * 8];
    pf[1] = *(const short8v*)&Ps[w][r][32 + g * 8];

    __builtin_amdgcn_s_setprio(1);
    #pragma unroll
    for (int c = 0; c < 2; ++c)
      #pragma unroll
      for (int hg = 0; hg < 4; ++hg)
        o[hg] = __builtin_amdgcn_mfma_f32_16x16x32_bf16(vb[hg][c], pf[c], o[hg], 0, 0, 0);
    __builtin_amdgcn_s_setprio(0);
  };

  if (t0 < t1) {
    loadK(t0, kbA);
    int t = t0;
    while (true) {
      body(t, kbA, kbB);
      if (++t >= t1) break;
      body(t, kbB, kbA);
      if (++t >= t1) break;
    }
  }

  if (w == 1) {
    if (g == 0) { ml[r][0] = mrun; ml[r][1] = lrun; }
    #pragma unroll
    for (int hg = 0; hg < 4; ++hg) *(f32x4*)&cmb[lane][hg * 4] = o[hg];
  }
  __syncthreads();
  if (w == 0) {
    const float m1 = ml[r][0], l1 = ml[r][1];
    const float mm = fmaxf(mrun, m1);
    const float sc0 = __expf(mrun - mm), sc1 = __expf(m1 - mm);
    const float inv = 1.f / (lrun * sc0 + l1 * sc1);
    #pragma unroll
    for (int hg = 0; hg < 4; ++hg) {
      const f32x4 o1 = *(const f32x4*)&cmb[lane][hg * 4];
      f32x4 res = (o[hg] * sc0 + o1 * sc1) * inv;
      *(f32x4*)(out + (tb + q0 + r) * H_ + hg * 16 + g * 4) = res;
    }
  }
}

extern "C" void kernel_launch(void* const* d_in, const int* in_sizes, int n_in,
                              void* d_out, int out_size, void* d_ws, size_t ws_size,
                              hipStream_t stream) {
  const float* x  = (const float*)d_in[0];
  const float* Wk = (const float*)d_in[1];
  const float* Wq = (const float*)d_in[2];
  const float* Wv = (const float*)d_in[3];
  float* out = (float*)d_out;

  __hip_bfloat16* Qb = (__hip_bfloat16*)d_ws;
  __hip_bfloat16* Kb = Qb + (size_t)B_ * T_ * H_;
  __hip_bfloat16* Vt = Kb + (size_t)B_ * T_ * H_;   // [B][64][T]
  __hip_bfloat16* Wf = Vt + (size_t)B_ * T_ * H_;   // fragment-major W, 384 KB

  prep_wf<<<(12 * 32 * 512) / 256, 256, 0, stream>>>(Wk, Wq, Wv, Wf);
  proj_mfma<<<(B_ * T_) / 32, 512, 0, stream>>>(x, Wf, Qb, Kb, Vt);
  attn_mfma<<<B_ * (T_ / 16), 128, 0, stream>>>(Qb, Kb, Vt, out);
}

// Round 8
// 59.684 us; speedup vs baseline: 2.2748x; 1.0727x over previous
//
#include <hip/hip_runtime.h>
#include <hip/hip_bf16.h>

#define B_ 8
#define T_ 2048
#define E_ 1024
#define H_ 64

typedef __attribute__((ext_vector_type(8))) short short8v;
typedef __attribute__((ext_vector_type(4))) float f32x4;

__device__ __forceinline__ unsigned short bfbits(float f) {
  return __builtin_bit_cast(unsigned short, __float2bfloat16(f));
}

__device__ __forceinline__ void gload_lds16(const void* g, void* l) {
  __builtin_amdgcn_global_load_lds(
      (const __attribute__((address_space(1))) unsigned*)g,
      (__attribute__((address_space(3))) unsigned*)l, 16, 0, 0);
}

// ---- prep: Wt[m][c][k] = Wm[k][c] (bf16), q-scale folded into m==1 ----
__global__ __launch_bounds__(256) void prep_wt(
    const float* __restrict__ Wk, const float* __restrict__ Wq,
    const float* __restrict__ Wv, __hip_bfloat16* __restrict__ Wt) {
  const int idx = blockIdx.x * 256 + threadIdx.x;  // 3*64*1024
  const int k = idx & 1023;
  const int c = (idx >> 10) & 63;
  const int m = idx >> 16;
  const float* W = (m == 0) ? Wk : (m == 1) ? Wq : Wv;
  float v = W[k * H_ + c];
  if (m == 1) v *= 0.03125f;  // 1024^-0.5
  Wt[idx] = __float2bfloat16(v);
}

// ---- projection: R3 staged-both structure + counted vmcnt pipeline ----
// 256 threads / 4 waves; wave w owns col-tile w (16 cols) of K,Q,V; 32 rows.
// x: 3-buffer distance-2 ring; W: 2-buffer distance-1; wait = vmcnt(2).
__global__ __launch_bounds__(256) void proj_mfma(
    const float* __restrict__ x, const __hip_bfloat16* __restrict__ Wt,
    __hip_bfloat16* __restrict__ Qb, __hip_bfloat16* __restrict__ Kb,
    __hip_bfloat16* __restrict__ Vt) {
  __shared__ float xs[3][32][64];            // 24 KB, slot16-swizzled by row&7
  __shared__ __hip_bfloat16 Ws[2][192][64];  // 48 KB, slot8-swizzled by row&7
  __shared__ __hip_bfloat16 rep[4][32][24];  // 6 KB epilogue repack
  const int tid = threadIdx.x;
  const int lane = tid & 63;
  const int w = tid >> 6;
  const int r = lane & 15, g = lane >> 4;
  const int r0 = blockIdx.x * 32;

  f32x4 acc[3][2];
  #pragma unroll
  for (int m = 0; m < 3; ++m)
    #pragma unroll
    for (int rt = 0; rt < 2; ++rt) acc[m][rt] = (f32x4){0.f, 0.f, 0.f, 0.f};

  auto stageX = [&](int buf, int kc) {  // 2 gload_lds per wave
    #pragma unroll
    for (int jj = 0; jj < 2; ++jj) {
      const int jb = w * 2 + jj;
      const int row = jb * 4 + (lane >> 4);
      const int sl = lane & 15;
      const int ssl = (sl & 8) | ((sl & 7) ^ (row & 7));
      gload_lds16(x + (size_t)(r0 + row) * E_ + kc + ssl * 4, &xs[buf][jb * 4][0]);
    }
  };
  auto stageW = [&](int buf, int kc) {  // 6 gload_lds per wave
    #pragma unroll
    for (int jj = 0; jj < 6; ++jj) {
      const int jb = w * 6 + jj;
      const int row = jb * 8 + (lane >> 3);
      const int sl = (lane & 7) ^ (row & 7);
      gload_lds16(Wt + (size_t)row * E_ + kc + sl * 8, &Ws[buf][jb * 8][0]);
    }
  };

  auto compute = [&](int bx, int bw) {
    #pragma unroll
    for (int kh = 0; kh < 2; ++kh) {
      short8v a[2];
      #pragma unroll
      for (int rt = 0; rt < 2; ++rt) {
        const int row = rt * 16 + r;
        const char* base = (const char*)&xs[bx][0][0] + row * 256;
        const int s0 = kh * 8 + ((2 * g + 0) ^ (r & 7));
        const int s1 = kh * 8 + ((2 * g + 1) ^ (r & 7));
        const f32x4 lo = *(const f32x4*)(base + s0 * 16);
        const f32x4 hi = *(const f32x4*)(base + s1 * 16);
        short8v t8;
        t8[0] = (short)bfbits(lo[0]); t8[1] = (short)bfbits(lo[1]);
        t8[2] = (short)bfbits(lo[2]); t8[3] = (short)bfbits(lo[3]);
        t8[4] = (short)bfbits(hi[0]); t8[5] = (short)bfbits(hi[1]);
        t8[6] = (short)bfbits(hi[2]); t8[7] = (short)bfbits(hi[3]);
        a[rt] = t8;
      }
      #pragma unroll
      for (int m = 0; m < 3; ++m) {
        const int rowW = m * 64 + w * 16 + r;
        const int sl = (kh * 4 + g) ^ (r & 7);
        const short8v bf =
            *(const short8v*)((const char*)&Ws[bw][0][0] + rowW * 128 + sl * 16);
        #pragma unroll
        for (int rt = 0; rt < 2; ++rt)
          acc[m][rt] = __builtin_amdgcn_mfma_f32_16x16x32_bf16(a[rt], bf, acc[m][rt], 0, 0, 0);
      }
    }
  };

  // prologue: X0, W0, X1 in that order; wait leaves X1 in flight
  stageX(0, 0);
  __builtin_amdgcn_sched_barrier(0);
  stageW(0, 0);
  __builtin_amdgcn_sched_barrier(0);
  stageX(1, 64);
  asm volatile("s_waitcnt vmcnt(2)" ::: "memory");
  __builtin_amdgcn_s_barrier();

  #pragma unroll
  for (int t = 0; t < 16; ++t) {
    if (t + 1 < 16) stageW((t + 1) & 1, (t + 1) * 64);
    __builtin_amdgcn_sched_barrier(0);
    if (t + 2 < 16) stageX((t + 2) % 3, (t + 2) * 64);
    __builtin_amdgcn_sched_barrier(0);
    compute(t % 3, t & 1);
    if (t + 2 < 16) {
      asm volatile("s_waitcnt vmcnt(2)" ::: "memory");  // W(t+1)+X(t+1) done
    } else if (t + 1 < 16) {
      asm volatile("s_waitcnt vmcnt(0)" ::: "memory");  // tail: drain W(15)
    }
    if (t + 1 < 16) __builtin_amdgcn_s_barrier();
  }

  // epilogue: per-wave repack K/Q to row-major; V direct transposed
  __hip_bfloat16* rp = &rep[w][0][0];
  #pragma unroll
  for (int m = 0; m < 2; ++m) {
    __hip_bfloat16* Pout = (m == 0) ? Kb : Qb;
    #pragma unroll
    for (int rt = 0; rt < 2; ++rt)
      #pragma unroll
      for (int reg = 0; reg < 4; ++reg)
        rp[(rt * 16 + g * 4 + reg) * 24 + r] = __float2bfloat16(acc[m][rt][reg]);
    asm volatile("s_waitcnt lgkmcnt(0)" ::: "memory");
    __builtin_amdgcn_sched_barrier(0);
    {
      const int row = lane >> 1, ch = lane & 1;
      *(uint4*)(Pout + (size_t)(r0 + row) * H_ + w * 16 + ch * 8) =
          *(const uint4*)(rp + row * 24 + ch * 8);
    }
    asm volatile("s_waitcnt lgkmcnt(0)" ::: "memory");
    __builtin_amdgcn_sched_barrier(0);
  }
  const int b = r0 >> 11;
  const int tt = r0 & 2047;
  #pragma unroll
  for (int rt = 0; rt < 2; ++rt) {
    ushort4 pk;
    pk.x = bfbits(acc[2][rt][0]); pk.y = bfbits(acc[2][rt][1]);
    pk.z = bfbits(acc[2][rt][2]); pk.w = bfbits(acc[2][rt][3]);
    *(ushort4*)(Vt + (size_t)(b * 64 + w * 16 + r) * T_ + tt + rt * 16 + g * 4) = pk;
  }
}

// ---- attention: barrier-free, swapped-QK, in-block key-split (round-4 exact) ----
__global__ __launch_bounds__(128, 2) void attn_mfma(
    const __hip_bfloat16* __restrict__ Qb, const __hip_bfloat16* __restrict__ Kb,
    const __hip_bfloat16* __restrict__ Vt, float* __restrict__ out) {
  __shared__ __hip_bfloat16 Ps[2][16][72];
  __shared__ float cmb[64][20];
  __shared__ float ml[16][2];
  const int tid = threadIdx.x;
  const int lane = tid & 63;
  const int w = tid >> 6;
  const int r = lane & 15, g = lane >> 4;
  const int blk = blockIdx.x;
  const int b = blk & 7;
  const int i = blk >> 3;  // 0..127
  const int s_ = i >> 5, j_ = i & 31;
  const int qt = (s_ == 0) ? j_ : (s_ == 1) ? (63 - j_) : (s_ == 2) ? (64 + j_) : (127 - j_);
  const int q0 = qt * 16;
  const size_t tb = (size_t)b * T_;
  const int bb = b * 64;

  const short8v qf0 = *(const short8v*)(Qb + (tb + q0 + r) * H_ + g * 8);
  const short8v qf1 = *(const short8v*)(Qb + (tb + q0 + r) * H_ + 32 + g * 8);

  f32x4 o[4];
  #pragma unroll
  for (int k2 = 0; k2 < 4; ++k2) o[k2] = (f32x4){0.f, 0.f, 0.f, 0.f};
  float mrun = -1e30f, lrun = 0.f;

  const int nt = (qt >> 2) + 1;
  const int h_ = (nt + 1) >> 1;
  const int t0 = w ? h_ : 0;
  const int t1 = w ? nt : h_;

  short8v kbA[4][2], kbB[4][2];
  auto loadK = [&](int t, short8v (&kb)[4][2]) {
    #pragma unroll
    for (int kg = 0; kg < 4; ++kg)
      #pragma unroll
      for (int c = 0; c < 2; ++c)
        kb[kg][c] = *(const short8v*)(Kb + (tb + t * 64 + kg * 16 + r) * H_ + c * 32 + g * 8);
  };

  auto body = [&](int t, short8v (&kbU)[4][2], short8v (&kbP)[4][2]) {
    short8v vb[4][2];
    #pragma unroll
    for (int hg = 0; hg < 4; ++hg)
      #pragma unroll
      for (int c = 0; c < 2; ++c)
        vb[hg][c] = *(const short8v*)(
            Vt + (size_t)(bb + hg * 16 + r) * T_ + t * 64 + c * 32 + g * 8);
    if (t + 1 < t1) loadK(t + 1, kbP);

    f32x4 s[4];
    #pragma unroll
    for (int k2 = 0; k2 < 4; ++k2) s[k2] = (f32x4){0.f, 0.f, 0.f, 0.f};
    __builtin_amdgcn_s_setprio(1);
    #pragma unroll
    for (int kg = 0; kg < 4; ++kg) {
      s[kg] = __builtin_amdgcn_mfma_f32_16x16x32_bf16(kbU[kg][0], qf0, s[kg], 0, 0, 0);
      s[kg] = __builtin_amdgcn_mfma_f32_16x16x32_bf16(kbU[kg][1], qf1, s[kg], 0, 0, 0);
    }
    __builtin_amdgcn_s_setprio(0);

    if (t == nt - 1) {
      #pragma unroll
      for (int kg = 0; kg < 4; ++kg)
        #pragma unroll
        for (int reg = 0; reg < 4; ++reg)
          if (t * 64 + kg * 16 + g * 4 + reg > q0 + r) s[kg][reg] = -1e30f;
    }

    float pm = s[0][0];
    #pragma unroll
    for (int kg = 0; kg < 4; ++kg)
      #pragma unroll
      for (int reg = 0; reg < 4; ++reg) pm = fmaxf(pm, s[kg][reg]);
    pm = fmaxf(pm, __shfl_xor(pm, 16));
    pm = fmaxf(pm, __shfl_xor(pm, 32));
    const float nm = fmaxf(mrun, pm);
    const float al = __expf(mrun - nm);
    mrun = nm;
    float p[4][4];
    float rs = 0.f;
    #pragma unroll
    for (int kg = 0; kg < 4; ++kg)
      #pragma unroll
      for (int reg = 0; reg < 4; ++reg) {
        p[kg][reg] = __expf(s[kg][reg] - nm);
        rs += p[kg][reg];
      }
    rs += __shfl_xor(rs, 16);
    rs += __shfl_xor(rs, 32);
    lrun = lrun * al + rs;
    #pragma unroll
    for (int hg = 0; hg < 4; ++hg) o[hg] *= al;

    #pragma unroll
    for (int kg = 0; kg < 4; ++kg) {
      ushort4 u;
      u.x = bfbits(p[kg][0]); u.y = bfbits(p[kg][1]);
      u.z = bfbits(p[kg][2]); u.w = bfbits(p[kg][3]);
      *(ushort4*)&Ps[w][r][kg * 16 + g * 4] = u;
    }
    short8v pf[2];
    pf[0] = *(const short8v*)&Ps[w][r][g * 8];
    pf[1] = *(const short8v*)&Ps[w][r][32 + g * 8];

    __builtin_amdgcn_s_setprio(1);
    #pragma unroll
    for (int c = 0; c < 2; ++c)
      #pragma unroll
      for (int hg = 0; hg < 4; ++hg)
        o[hg] = __builtin_amdgcn_mfma_f32_16x16x32_bf16(vb[hg][c], pf[c], o[hg], 0, 0, 0);
    __builtin_amdgcn_s_setprio(0);
  };

  if (t0 < t1) {
    loadK(t0, kbA);
    int t = t0;
    while (true) {
      body(t, kbA, kbB);
      if (++t >= t1) break;
      body(t, kbB, kbA);
      if (++t >= t1) break;
    }
  }

  if (w == 1) {
    if (g == 0) { ml[r][0] = mrun; ml[r][1] = lrun; }
    #pragma unroll
    for (int hg = 0; hg < 4; ++hg) *(f32x4*)&cmb[lane][hg * 4] = o[hg];
  }
  __syncthreads();
  if (w == 0) {
    const float m1 = ml[r][0], l1 = ml[r][1];
    const float mm = fmaxf(mrun, m1);
    const float sc0 = __expf(mrun - mm), sc1 = __expf(m1 - mm);
    const float inv = 1.f / (lrun * sc0 + l1 * sc1);
    #pragma unroll
    for (int hg = 0; hg < 4; ++hg) {
      const f32x4 o1 = *(const f32x4*)&cmb[lane][hg * 4];
      f32x4 res = (o[hg] * sc0 + o1 * sc1) * inv;
      *(f32x4*)(out + (tb + q0 + r) * H_ + hg * 16 + g * 4) = res;
    }
  }
}

extern "C" void kernel_launch(void* const* d_in, const int* in_sizes, int n_in,
                              void* d_out, int out_size, void* d_ws, size_t ws_size,
                              hipStream_t stream) {
  const float* x  = (const float*)d_in[0];
  const float* Wk = (const float*)d_in[1];
  const float* Wq = (const float*)d_in[2];
  const float* Wv = (const float*)d_in[3];
  float* out = (float*)d_out;

  __hip_bfloat16* Qb = (__hip_bfloat16*)d_ws;
  __hip_bfloat16* Kb = Qb + (size_t)B_ * T_ * H_;
  __hip_bfloat16* Vt = Kb + (size_t)B_ * T_ * H_;   // [B][64][T]
  __hip_bfloat16* Wt = Vt + (size_t)B_ * T_ * H_;   // [3][64][1024]

  prep_wt<<<(3 * H_ * E_) / 256, 256, 0, stream>>>(Wk, Wq, Wv, Wt);
  proj_mfma<<<(B_ * T_) / 32, 256, 0, stream>>>(x, Wt, Qb, Kb, Vt);
  attn_mfma<<<B_ * (T_ / 16), 128, 0, stream>>>(Qb, Kb, Vt, out);
}